// Round 9
// baseline (224.394 us; speedup 1.0000x reference)
//
#include <hip/hip_runtime.h>

// ConnectivityLoss R9: exact R6 structure (proven 123us, 84 VGPR, no scratch)
// plus two zero-pressure deltas:
//  - contour = maxpool3(B) - B (inner relu is an identity: mx >= B always).
//  - wave-atomic reduction tail (no red[] LDS round-trip, no final barrier).
// EMPIRICAL RULES (R5/R7/R8): launch_bounds(256,4) => 64-VGPR target =>
// ~1.4 GB scratch. Extra R8 temporaries in divergent border paths (R8) =>
// 98 MB scratch even at (256,3). Keep (256,3); keep per-lane border fixups;
// check WRITE_SIZE ~ 64 KB every round.

#define IMG 512
#define TW  32            // output tile width  (16 x-tiles)
#define TH  128           // output tile height (4 y-tiles)
#define SKW 34            // skeleton stash cols [11,44]
#define SKH 130           // skeleton stash rows [11,140]
#define XROW 68           // exchange row stride (floats)
#define XBUF (8*XROW)     // 4 waves x {top,bot}
#define NT  256

struct alignas(16) R8 { float v[8]; };

__device__ __forceinline__ float f3min(float a, float b, float c) {
    return fminf(fminf(a, b), c);
}
__device__ __forceinline__ float f3max(float a, float b, float c) {
    return fmaxf(fmaxf(a, b), c);
}
__device__ __forceinline__ float dpp_up1(float x) {   // lane i <- i-1
    int r = __builtin_amdgcn_update_dpp(
        0, __builtin_bit_cast(int, x), 0x111, 0xF, 0xF, true); // row_shr:1
    return __builtin_bit_cast(float, r);
}
__device__ __forceinline__ float dpp_dn1(float x) {   // lane i <- i+1
    int r = __builtin_amdgcn_update_dpp(
        0, __builtin_bit_cast(int, x), 0x101, 0xF, 0xF, true); // row_shl:1
    return __builtin_bit_cast(float, r);
}
__device__ __forceinline__ float bpermf(int addr, float x) {
    return __builtin_bit_cast(float,
        __builtin_amdgcn_ds_bpermute(addr, __builtin_bit_cast(int, x)));
}

// horizontal 3-tap; le/ri from strip s-1/s+1 (lane -8/+8, precomputed addrs).
// fixL/fixR: clamped-window at image cols 0/511 (drop out-of-image tap).
template<bool MN>
__device__ __forceinline__ void hrow(const R8& r, R8& h, bool fixL, bool fixR,
                                     int aL, int aR) {
    float le = bpermf(aL, r.v[7]);
    float ri = bpermf(aR, r.v[0]);
    if (MN) {
        h.v[0] = f3min(le,     r.v[0], r.v[1]);
        h.v[1] = f3min(r.v[0], r.v[1], r.v[2]);
        h.v[2] = f3min(r.v[1], r.v[2], r.v[3]);
        h.v[3] = f3min(r.v[2], r.v[3], r.v[4]);
        h.v[4] = f3min(r.v[3], r.v[4], r.v[5]);
        h.v[5] = f3min(r.v[4], r.v[5], r.v[6]);
        h.v[6] = f3min(r.v[5], r.v[6], r.v[7]);
        h.v[7] = f3min(r.v[6], r.v[7], ri);
        if (fixL) h.v[4] = fminf(r.v[4], r.v[5]);   // gx==0
        if (fixR) h.v[3] = fminf(r.v[2], r.v[3]);   // gx==511
    } else {
        h.v[0] = f3max(le,     r.v[0], r.v[1]);
        h.v[1] = f3max(r.v[0], r.v[1], r.v[2]);
        h.v[2] = f3max(r.v[1], r.v[2], r.v[3]);
        h.v[3] = f3max(r.v[2], r.v[3], r.v[4]);
        h.v[4] = f3max(r.v[3], r.v[4], r.v[5]);
        h.v[5] = f3max(r.v[4], r.v[5], r.v[6]);
        h.v[6] = f3max(r.v[5], r.v[6], r.v[7]);
        h.v[7] = f3max(r.v[6], r.v[7], ri);
        if (fixL) h.v[4] = fmaxf(r.v[4], r.v[5]);
        if (fixR) h.v[3] = fmaxf(r.v[2], r.v[3]);
    }
}

__global__ __launch_bounds__(NT, 3)
void skel_conn_loss(const float* __restrict__ pred,
                    const float* __restrict__ target,
                    float* __restrict__ out)
{
    __shared__ float X[2*XBUF];          // boundary-row exchange dbuf (4.35KB)
    __shared__ float SKP[SKH*SKW];       // pred skeleton
    __shared__ float SKT[SKH*SKW];       // target skeleton

    const int tid  = threadIdx.x;
    const int wv   = tid >> 6;           // wave 0..3 owns rows 40w..40w+39
    const int lane = tid & 63;
    const int s    = lane >> 3;          // 8-col strip
    const int gq   = lane & 7;           // row group (5 rows); +-1 == lane+-1
    const int img  = blockIdx.x >> 6;
    const int rem  = blockIdx.x & 63;
    const int ty0  = (rem >> 4) * TH;
    const int tx0  = (rem & 15) * TW;

    const int c0  = 8*s;
    const int r0  = 40*wv + 5*gq;
    const int gx0 = tx0 - 12 + c0;
    const bool xin = (tx0 > 0) && (tx0 + TW < IMG);

    const bool lB = (tx0 == 0), rB = (tx0 + TW == IMG);
    const bool tB = (ty0 == 0), bB = (ty0 + TH == IMG);
    const bool fixL = lB && (s == 1);                // col 12 == gx 0
    const bool fixR = rB && (s == 5);                // col 43 == gx 511
    const bool vfT  = tB && (wv == 0) && (gq == 2);  // row 12 == gy 0 (i==2)
    const bool vfB  = bB && (wv == 3) && (gq == 3);  // row 139 == gy 511 (i==4)
    const int  sw   = 8*s + 4*(s >> 2);              // bank-swizzled exch col
    const int  aL   = ((lane - 8) & 63) * 4;         // bpermute addrs
    const int  aR   = ((lane + 8) & 63) * 4;

    R8 A[5], Bv[5];
    int xb = 0;

    #pragma unroll 1
    for (int t = 0; t < 2; ++t) {
        const float* __restrict__ src =
            (t ? target : pred) + (size_t)img * (IMG * IMG);

        // ---- load strip (addresses clamped; OOB values never consumed) ----
        #pragma unroll
        for (int i = 0; i < 5; ++i) {
            int gy = min(max(ty0 - 12 + r0 + i, 0), IMG - 1);
            const float* rp = src + gy * IMG;
            if (xin) {
                *(float4*)&A[i].v[0] = *(const float4*)(rp + gx0);
                *(float4*)&A[i].v[4] = *(const float4*)(rp + gx0 + 4);
            } else {
                #pragma unroll
                for (int j = 0; j < 8; ++j)
                    A[i].v[j] = rp[min(max(gx0 + j, 0), IMG - 1)];
            }
        }

        #pragma unroll 1
        for (int it = 0; it < 5; ++it) {
            // ================= pass 1: Bv = minpool3(A) =================
            {
                R8 w0, w1, w2, w3, w4, abh, beh;
                hrow<true>(A[4], w4, fixL, fixR, aL, aR);   // feeds exch+DPP
                hrow<true>(A[0], w0, fixL, fixR, aL, aR);
                float* Xb = X + xb * XBUF;
                if (gq == 0) {
                    float* p = Xb + (2*wv) * XROW + sw;
                    *(float4*)p       = *(const float4*)&w0.v[0];
                    *(float4*)(p + 4) = *(const float4*)&w0.v[4];
                }
                if (gq == 7) {
                    float* p = Xb + (2*wv + 1) * XROW + sw;
                    *(float4*)p       = *(const float4*)&w4.v[0];
                    *(float4*)(p + 4) = *(const float4*)&w4.v[4];
                }
                __syncthreads();
                #pragma unroll
                for (int j = 0; j < 8; ++j) {
                    abh.v[j] = dpp_up1(w4.v[j]);   // group above's bottom
                    beh.v[j] = dpp_dn1(w0.v[j]);   // group below's top
                }
                if (gq == 0) {
                    if (wv) {
                        const float* p = Xb + (2*wv - 1) * XROW + sw;
                        *(float4*)&abh.v[0] = *(const float4*)p;
                        *(float4*)&abh.v[4] = *(const float4*)(p + 4);
                    } else abh = w0;               // tile-edge garbage margin
                }
                if (gq == 7) {
                    if (wv < 3) {
                        const float* p = Xb + (2*wv + 2) * XROW + sw;
                        *(float4*)&beh.v[0] = *(const float4*)p;
                        *(float4*)&beh.v[4] = *(const float4*)(p + 4);
                    } else beh = w4;
                }
                hrow<true>(A[1], w1, fixL, fixR, aL, aR);
                #pragma unroll
                for (int j = 0; j < 8; ++j)
                    Bv[0].v[j] = f3min(abh.v[j], w0.v[j], w1.v[j]);
                hrow<true>(A[2], w2, fixL, fixR, aL, aR);
                #pragma unroll
                for (int j = 0; j < 8; ++j)
                    Bv[1].v[j] = f3min(w0.v[j], w1.v[j], w2.v[j]);
                hrow<true>(A[3], w3, fixL, fixR, aL, aR);
                #pragma unroll
                for (int j = 0; j < 8; ++j) {
                    Bv[2].v[j] = vfT ? fminf(w2.v[j], w3.v[j])
                                     : f3min(w1.v[j], w2.v[j], w3.v[j]);
                    Bv[3].v[j] = f3min(w2.v[j], w3.v[j], w4.v[j]);
                    Bv[4].v[j] = vfB ? fminf(w3.v[j], w4.v[j])
                                     : f3min(w3.v[j], w4.v[j], beh.v[j]);
                }
                xb ^= 1;
            }
            // == pass 2: A = relu(A - (maxpool3(Bv) - Bv)); mx>=Bv exact ==
            {
                R8 u0, u1, u2, u3, u4, abh, beh;
                hrow<false>(Bv[4], u4, fixL, fixR, aL, aR);
                hrow<false>(Bv[0], u0, fixL, fixR, aL, aR);
                float* Xb = X + xb * XBUF;
                if (gq == 0) {
                    float* p = Xb + (2*wv) * XROW + sw;
                    *(float4*)p       = *(const float4*)&u0.v[0];
                    *(float4*)(p + 4) = *(const float4*)&u0.v[4];
                }
                if (gq == 7) {
                    float* p = Xb + (2*wv + 1) * XROW + sw;
                    *(float4*)p       = *(const float4*)&u4.v[0];
                    *(float4*)(p + 4) = *(const float4*)&u4.v[4];
                }
                __syncthreads();
                #pragma unroll
                for (int j = 0; j < 8; ++j) {
                    abh.v[j] = dpp_up1(u4.v[j]);
                    beh.v[j] = dpp_dn1(u0.v[j]);
                }
                if (gq == 0) {
                    if (wv) {
                        const float* p = Xb + (2*wv - 1) * XROW + sw;
                        *(float4*)&abh.v[0] = *(const float4*)p;
                        *(float4*)&abh.v[4] = *(const float4*)(p + 4);
                    } else abh = u0;
                }
                if (gq == 7) {
                    if (wv < 3) {
                        const float* p = Xb + (2*wv + 2) * XROW + sw;
                        *(float4*)&beh.v[0] = *(const float4*)p;
                        *(float4*)&beh.v[4] = *(const float4*)(p + 4);
                    } else beh = u4;
                }
                // ct = mx - Bv (>= 0 exactly: center is in its own window)
                #define UPD(i, MXE)                                            \
                    _Pragma("unroll")                                          \
                    for (int j = 0; j < 8; ++j) {                              \
                        float ct = (MXE) - Bv[i].v[j];                         \
                        A[i].v[j] = fmaxf(A[i].v[j] - ct, 0.0f);               \
                    }
                hrow<false>(Bv[1], u1, fixL, fixR, aL, aR);
                UPD(0, f3max(abh.v[j], u0.v[j], u1.v[j]))
                hrow<false>(Bv[2], u2, fixL, fixR, aL, aR);
                UPD(1, f3max(u0.v[j], u1.v[j], u2.v[j]))
                hrow<false>(Bv[3], u3, fixL, fixR, aL, aR);
                UPD(2, vfT ? fmaxf(u2.v[j], u3.v[j])
                           : f3max(u1.v[j], u2.v[j], u3.v[j]))
                UPD(3, f3max(u2.v[j], u3.v[j], u4.v[j]))
                UPD(4, vfB ? fmaxf(u3.v[j], u4.v[j])
                           : f3max(u3.v[j], u4.v[j], beh.v[j]))
                #undef UPD
                xb ^= 1;
            }
        }

        // ---- stash skeleton region [11,140]x[11,44] to LDS ----
        {
            float* SK = t ? SKT : SKP;
            #pragma unroll
            for (int i = 0; i < 5; ++i) {
                int pr = r0 + i;
                if (pr >= 11 && pr <= 140) {
                    #pragma unroll
                    for (int j = 0; j < 8; ++j) {
                        int pc = c0 + j;
                        if (pc >= 11 && pc <= 44)
                            SK[(pr - 11) * SKW + (pc - 11)] = A[i].v[j];
                    }
                }
            }
        }
    }
    __syncthreads();

    // ---- epilogue: rolling-column sumpool3 + indicators + loss ----
    // thread = column cx, 16 rows. SK row k holds global row ty0 + k - 1.
    const int cx  = tid & 31;
    const int ry0 = (tid >> 5) * 16;
    const int gx  = tx0 + cx;
    const float xl = (gx >= 1)      ? 1.0f : 0.0f;
    const float xr = (gx + 1 < IMG) ? 1.0f : 0.0f;

    auto hs = [&](const float* __restrict__ SK, int k) -> float {
        const float* p = SK + k * SKW + cx;   // p[0]=dx-1, p[1]=dx0, p[2]=dx+1
        return p[1] + xl * p[0] + xr * p[2];  // garbage finite, masked by 0
    };

    float acc = 0.0f;
    float hp0, hp1, ht0, ht1;
    {
        float vT = ((unsigned)(ty0 + ry0 - 1) < IMG) ? 1.0f : 0.0f;
        hp0 = vT * hs(SKP, ry0);
        ht0 = vT * hs(SKT, ry0);
        hp1 = hs(SKP, ry0 + 1);               // always in-image
        ht1 = hs(SKT, ry0 + 1);
    }
    #pragma unroll
    for (int r = 0; r < 16; ++r) {
        int k2 = ry0 + r + 2;
        float vB = ((unsigned)(ty0 + k2 - 1) < IMG) ? 1.0f : 0.0f;
        float hp2 = vB * hs(SKP, k2);
        float ht2 = vB * hs(SKT, k2);
        float pn = hp0 + hp1 + hp2;
        float tn = ht0 + ht1 + ht2;
        float ps = SKP[(ry0 + r + 1) * SKW + cx + 1];
        float ts = SKT[(ry0 + r + 1) * SKW + cx + 1];
        float pon = (ps > 0.5f) ? 1.0f : 0.0f;
        float ton = (ts > 0.5f) ? 1.0f : 0.0f;
        float pe = (pn == 2.0f) ? pon : 0.0f;
        float te = (tn == 2.0f) ? ton : 0.0f;
        float pc = (pn >= 4.0f) ? pon : 0.0f;
        float tc = (tn >= 4.0f) ? ton : 0.0f;
        float ds = ps - ts, de = pe - te, dc = pc - tc;
        acc += 0.6f * ds * ds + 0.2f * (de * de + dc * dc);
        hp0 = hp1; hp1 = hp2;
        ht0 = ht1; ht1 = ht2;
    }

    // ---- wave-level reduction, one atomic per wave ----
    #pragma unroll
    for (int off = 32; off >= 1; off >>= 1)
        acc += __shfl_down(acc, off, 64);
    if (lane == 0)
        atomicAdd(out, acc * (1.0f / 8388608.0f));  // N = 32*512*512 = 2^23
}

extern "C" void kernel_launch(void* const* d_in, const int* in_sizes, int n_in,
                              void* d_out, int out_size, void* d_ws, size_t ws_size,
                              hipStream_t stream) {
    const float* pred   = (const float*)d_in[0];
    const float* target = (const float*)d_in[1];
    float* out = (float*)d_out;
    hipMemsetAsync(d_out, 0, sizeof(float) * (out_size > 0 ? out_size : 1), stream);
    const int nblocks = 32 * 64;   // 32 images x (4x16) tiles
    skel_conn_loss<<<nblocks, NT, 0, stream>>>(pred, target, out);
}

// Round 10
// 187.988 us; speedup vs baseline: 1.1937x; 1.1937x over previous
//
#include <hip/hip_runtime.h>

// ConnectivityLoss R10: R6 structure + inner-relu deletion; block-atomic tail.
// EMPIRICAL RULES (R5/R7/R8/R9):
//  - launch_bounds(256,4) => backend targets 64 VGPR => ~1.4 GB scratch. Keep (256,3).
//  - Extra R8 temporaries in divergent border paths => scratch even at (256,3).
//    Keep per-lane fixL/fixR/vfT/vfB cndmask fixups (R6 form).
//  - Same-address atomics: one per BLOCK (2048) is fine; one per WAVE (8192)
//    serializes cross-XCD and cost ~+100us (R9). Keep LDS tail reduction.
//  - Tripwire every round: WRITE_SIZE must stay ~64 KB.

#define IMG 512
#define TW  32            // output tile width  (16 x-tiles)
#define TH  128           // output tile height (4 y-tiles)
#define SKW 34            // skeleton stash cols [11,44]
#define SKH 130           // skeleton stash rows [11,140]
#define XROW 68           // exchange row stride (floats)
#define XBUF (8*XROW)     // 4 waves x {top,bot}
#define NT  256

struct alignas(16) R8 { float v[8]; };

__device__ __forceinline__ float f3min(float a, float b, float c) {
    return fminf(fminf(a, b), c);
}
__device__ __forceinline__ float f3max(float a, float b, float c) {
    return fmaxf(fmaxf(a, b), c);
}
__device__ __forceinline__ float dpp_up1(float x) {   // lane i <- i-1
    int r = __builtin_amdgcn_update_dpp(
        0, __builtin_bit_cast(int, x), 0x111, 0xF, 0xF, true); // row_shr:1
    return __builtin_bit_cast(float, r);
}
__device__ __forceinline__ float dpp_dn1(float x) {   // lane i <- i+1
    int r = __builtin_amdgcn_update_dpp(
        0, __builtin_bit_cast(int, x), 0x101, 0xF, 0xF, true); // row_shl:1
    return __builtin_bit_cast(float, r);
}
__device__ __forceinline__ float bpermf(int addr, float x) {
    return __builtin_bit_cast(float,
        __builtin_amdgcn_ds_bpermute(addr, __builtin_bit_cast(int, x)));
}

// horizontal 3-tap; le/ri from strip s-1/s+1 (lane -8/+8, precomputed addrs).
// fixL/fixR: clamped-window at image cols 0/511 (drop out-of-image tap).
template<bool MN>
__device__ __forceinline__ void hrow(const R8& r, R8& h, bool fixL, bool fixR,
                                     int aL, int aR) {
    float le = bpermf(aL, r.v[7]);
    float ri = bpermf(aR, r.v[0]);
    if (MN) {
        h.v[0] = f3min(le,     r.v[0], r.v[1]);
        h.v[1] = f3min(r.v[0], r.v[1], r.v[2]);
        h.v[2] = f3min(r.v[1], r.v[2], r.v[3]);
        h.v[3] = f3min(r.v[2], r.v[3], r.v[4]);
        h.v[4] = f3min(r.v[3], r.v[4], r.v[5]);
        h.v[5] = f3min(r.v[4], r.v[5], r.v[6]);
        h.v[6] = f3min(r.v[5], r.v[6], r.v[7]);
        h.v[7] = f3min(r.v[6], r.v[7], ri);
        if (fixL) h.v[4] = fminf(r.v[4], r.v[5]);   // gx==0
        if (fixR) h.v[3] = fminf(r.v[2], r.v[3]);   // gx==511
    } else {
        h.v[0] = f3max(le,     r.v[0], r.v[1]);
        h.v[1] = f3max(r.v[0], r.v[1], r.v[2]);
        h.v[2] = f3max(r.v[1], r.v[2], r.v[3]);
        h.v[3] = f3max(r.v[2], r.v[3], r.v[4]);
        h.v[4] = f3max(r.v[3], r.v[4], r.v[5]);
        h.v[5] = f3max(r.v[4], r.v[5], r.v[6]);
        h.v[6] = f3max(r.v[5], r.v[6], r.v[7]);
        h.v[7] = f3max(r.v[6], r.v[7], ri);
        if (fixL) h.v[4] = fmaxf(r.v[4], r.v[5]);
        if (fixR) h.v[3] = fmaxf(r.v[2], r.v[3]);
    }
}

__global__ __launch_bounds__(NT, 3)
void skel_conn_loss(const float* __restrict__ pred,
                    const float* __restrict__ target,
                    float* __restrict__ out)
{
    __shared__ float X[2*XBUF];          // boundary-row exchange dbuf (4.35KB)
    __shared__ float SKP[SKH*SKW];       // pred skeleton
    __shared__ float SKT[SKH*SKW];       // target skeleton
    __shared__ float red[4];

    const int tid  = threadIdx.x;
    const int wv   = tid >> 6;           // wave 0..3 owns rows 40w..40w+39
    const int lane = tid & 63;
    const int s    = lane >> 3;          // 8-col strip
    const int gq   = lane & 7;           // row group (5 rows); +-1 == lane+-1
    const int img  = blockIdx.x >> 6;
    const int rem  = blockIdx.x & 63;
    const int ty0  = (rem >> 4) * TH;
    const int tx0  = (rem & 15) * TW;

    const int c0  = 8*s;
    const int r0  = 40*wv + 5*gq;
    const int gx0 = tx0 - 12 + c0;
    const bool xin = (tx0 > 0) && (tx0 + TW < IMG);

    const bool lB = (tx0 == 0), rB = (tx0 + TW == IMG);
    const bool tB = (ty0 == 0), bB = (ty0 + TH == IMG);
    const bool fixL = lB && (s == 1);                // col 12 == gx 0
    const bool fixR = rB && (s == 5);                // col 43 == gx 511
    const bool vfT  = tB && (wv == 0) && (gq == 2);  // row 12 == gy 0 (i==2)
    const bool vfB  = bB && (wv == 3) && (gq == 3);  // row 139 == gy 511 (i==4)
    const int  sw   = 8*s + 4*(s >> 2);              // bank-swizzled exch col
    const int  aL   = ((lane - 8) & 63) * 4;         // bpermute addrs
    const int  aR   = ((lane + 8) & 63) * 4;

    R8 A[5], Bv[5];
    int xb = 0;

    #pragma unroll 1
    for (int t = 0; t < 2; ++t) {
        const float* __restrict__ src =
            (t ? target : pred) + (size_t)img * (IMG * IMG);

        // ---- load strip (addresses clamped; OOB values never consumed) ----
        #pragma unroll
        for (int i = 0; i < 5; ++i) {
            int gy = min(max(ty0 - 12 + r0 + i, 0), IMG - 1);
            const float* rp = src + gy * IMG;
            if (xin) {
                *(float4*)&A[i].v[0] = *(const float4*)(rp + gx0);
                *(float4*)&A[i].v[4] = *(const float4*)(rp + gx0 + 4);
            } else {
                #pragma unroll
                for (int j = 0; j < 8; ++j)
                    A[i].v[j] = rp[min(max(gx0 + j, 0), IMG - 1)];
            }
        }

        #pragma unroll 1
        for (int it = 0; it < 5; ++it) {
            // ================= pass 1: Bv = minpool3(A) =================
            {
                R8 w0, w1, w2, w3, w4, abh, beh;
                hrow<true>(A[4], w4, fixL, fixR, aL, aR);   // feeds exch+DPP
                hrow<true>(A[0], w0, fixL, fixR, aL, aR);
                float* Xb = X + xb * XBUF;
                if (gq == 0) {
                    float* p = Xb + (2*wv) * XROW + sw;
                    *(float4*)p       = *(const float4*)&w0.v[0];
                    *(float4*)(p + 4) = *(const float4*)&w0.v[4];
                }
                if (gq == 7) {
                    float* p = Xb + (2*wv + 1) * XROW + sw;
                    *(float4*)p       = *(const float4*)&w4.v[0];
                    *(float4*)(p + 4) = *(const float4*)&w4.v[4];
                }
                __syncthreads();
                #pragma unroll
                for (int j = 0; j < 8; ++j) {
                    abh.v[j] = dpp_up1(w4.v[j]);   // group above's bottom
                    beh.v[j] = dpp_dn1(w0.v[j]);   // group below's top
                }
                if (gq == 0) {
                    if (wv) {
                        const float* p = Xb + (2*wv - 1) * XROW + sw;
                        *(float4*)&abh.v[0] = *(const float4*)p;
                        *(float4*)&abh.v[4] = *(const float4*)(p + 4);
                    } else abh = w0;               // tile-edge garbage margin
                }
                if (gq == 7) {
                    if (wv < 3) {
                        const float* p = Xb + (2*wv + 2) * XROW + sw;
                        *(float4*)&beh.v[0] = *(const float4*)p;
                        *(float4*)&beh.v[4] = *(const float4*)(p + 4);
                    } else beh = w4;
                }
                hrow<true>(A[1], w1, fixL, fixR, aL, aR);
                #pragma unroll
                for (int j = 0; j < 8; ++j)
                    Bv[0].v[j] = f3min(abh.v[j], w0.v[j], w1.v[j]);
                hrow<true>(A[2], w2, fixL, fixR, aL, aR);
                #pragma unroll
                for (int j = 0; j < 8; ++j)
                    Bv[1].v[j] = f3min(w0.v[j], w1.v[j], w2.v[j]);
                hrow<true>(A[3], w3, fixL, fixR, aL, aR);
                #pragma unroll
                for (int j = 0; j < 8; ++j) {
                    Bv[2].v[j] = vfT ? fminf(w2.v[j], w3.v[j])
                                     : f3min(w1.v[j], w2.v[j], w3.v[j]);
                    Bv[3].v[j] = f3min(w2.v[j], w3.v[j], w4.v[j]);
                    Bv[4].v[j] = vfB ? fminf(w3.v[j], w4.v[j])
                                     : f3min(w3.v[j], w4.v[j], beh.v[j]);
                }
                xb ^= 1;
            }
            // == pass 2: A = relu(A - (maxpool3(Bv) - Bv)); mx>=Bv exact ==
            {
                R8 u0, u1, u2, u3, u4, abh, beh;
                hrow<false>(Bv[4], u4, fixL, fixR, aL, aR);
                hrow<false>(Bv[0], u0, fixL, fixR, aL, aR);
                float* Xb = X + xb * XBUF;
                if (gq == 0) {
                    float* p = Xb + (2*wv) * XROW + sw;
                    *(float4*)p       = *(const float4*)&u0.v[0];
                    *(float4*)(p + 4) = *(const float4*)&u0.v[4];
                }
                if (gq == 7) {
                    float* p = Xb + (2*wv + 1) * XROW + sw;
                    *(float4*)p       = *(const float4*)&u4.v[0];
                    *(float4*)(p + 4) = *(const float4*)&u4.v[4];
                }
                __syncthreads();
                #pragma unroll
                for (int j = 0; j < 8; ++j) {
                    abh.v[j] = dpp_up1(u4.v[j]);
                    beh.v[j] = dpp_dn1(u0.v[j]);
                }
                if (gq == 0) {
                    if (wv) {
                        const float* p = Xb + (2*wv - 1) * XROW + sw;
                        *(float4*)&abh.v[0] = *(const float4*)p;
                        *(float4*)&abh.v[4] = *(const float4*)(p + 4);
                    } else abh = u0;
                }
                if (gq == 7) {
                    if (wv < 3) {
                        const float* p = Xb + (2*wv + 2) * XROW + sw;
                        *(float4*)&beh.v[0] = *(const float4*)p;
                        *(float4*)&beh.v[4] = *(const float4*)(p + 4);
                    } else beh = u4;
                }
                // ct = mx - Bv (>= 0 exactly: center is in its own window)
                #define UPD(i, MXE)                                            \
                    _Pragma("unroll")                                          \
                    for (int j = 0; j < 8; ++j) {                              \
                        float ct = (MXE) - Bv[i].v[j];                         \
                        A[i].v[j] = fmaxf(A[i].v[j] - ct, 0.0f);               \
                    }
                hrow<false>(Bv[1], u1, fixL, fixR, aL, aR);
                UPD(0, f3max(abh.v[j], u0.v[j], u1.v[j]))
                hrow<false>(Bv[2], u2, fixL, fixR, aL, aR);
                UPD(1, f3max(u0.v[j], u1.v[j], u2.v[j]))
                hrow<false>(Bv[3], u3, fixL, fixR, aL, aR);
                UPD(2, vfT ? fmaxf(u2.v[j], u3.v[j])
                           : f3max(u1.v[j], u2.v[j], u3.v[j]))
                UPD(3, f3max(u2.v[j], u3.v[j], u4.v[j]))
                UPD(4, vfB ? fmaxf(u3.v[j], u4.v[j])
                           : f3max(u3.v[j], u4.v[j], beh.v[j]))
                #undef UPD
                xb ^= 1;
            }
        }

        // ---- stash skeleton region [11,140]x[11,44] to LDS ----
        {
            float* SK = t ? SKT : SKP;
            #pragma unroll
            for (int i = 0; i < 5; ++i) {
                int pr = r0 + i;
                if (pr >= 11 && pr <= 140) {
                    #pragma unroll
                    for (int j = 0; j < 8; ++j) {
                        int pc = c0 + j;
                        if (pc >= 11 && pc <= 44)
                            SK[(pr - 11) * SKW + (pc - 11)] = A[i].v[j];
                    }
                }
            }
        }
    }
    __syncthreads();

    // ---- epilogue: rolling-column sumpool3 + indicators + loss ----
    // thread = column cx, 16 rows. SK row k holds global row ty0 + k - 1.
    const int cx  = tid & 31;
    const int ry0 = (tid >> 5) * 16;
    const int gx  = tx0 + cx;
    const float xl = (gx >= 1)      ? 1.0f : 0.0f;
    const float xr = (gx + 1 < IMG) ? 1.0f : 0.0f;

    auto hs = [&](const float* __restrict__ SK, int k) -> float {
        const float* p = SK + k * SKW + cx;   // p[0]=dx-1, p[1]=dx0, p[2]=dx+1
        return p[1] + xl * p[0] + xr * p[2];  // garbage finite, masked by 0
    };

    float acc = 0.0f;
    float hp0, hp1, ht0, ht1;
    {
        float vT = ((unsigned)(ty0 + ry0 - 1) < IMG) ? 1.0f : 0.0f;
        hp0 = vT * hs(SKP, ry0);
        ht0 = vT * hs(SKT, ry0);
        hp1 = hs(SKP, ry0 + 1);               // always in-image
        ht1 = hs(SKT, ry0 + 1);
    }
    #pragma unroll
    for (int r = 0; r < 16; ++r) {
        int k2 = ry0 + r + 2;
        float vB = ((unsigned)(ty0 + k2 - 1) < IMG) ? 1.0f : 0.0f;
        float hp2 = vB * hs(SKP, k2);
        float ht2 = vB * hs(SKT, k2);
        float pn = hp0 + hp1 + hp2;
        float tn = ht0 + ht1 + ht2;
        float ps = SKP[(ry0 + r + 1) * SKW + cx + 1];
        float ts = SKT[(ry0 + r + 1) * SKW + cx + 1];
        float pon = (ps > 0.5f) ? 1.0f : 0.0f;
        float ton = (ts > 0.5f) ? 1.0f : 0.0f;
        float pe = (pn == 2.0f) ? pon : 0.0f;
        float te = (tn == 2.0f) ? ton : 0.0f;
        float pc = (pn >= 4.0f) ? pon : 0.0f;
        float tc = (tn >= 4.0f) ? ton : 0.0f;
        float ds = ps - ts, de = pe - te, dc = pc - tc;
        acc += 0.6f * ds * ds + 0.2f * (de * de + dc * dc);
        hp0 = hp1; hp1 = hp2;
        ht0 = ht1; ht1 = ht2;
    }

    // ---- block reduction -> ONE atomic per block (2048 total; per-wave
    // 8192 same-address atomics cost +100us cross-XCD — R9) ----
    #pragma unroll
    for (int off = 32; off >= 1; off >>= 1)
        acc += __shfl_down(acc, off, 64);
    if (lane == 0) red[wv] = acc;
    __syncthreads();
    if (tid == 0) {
        float sum = red[0] + red[1] + red[2] + red[3];
        atomicAdd(out, sum * (1.0f / 8388608.0f));  // N = 32*512*512 = 2^23
    }
}

extern "C" void kernel_launch(void* const* d_in, const int* in_sizes, int n_in,
                              void* d_out, int out_size, void* d_ws, size_t ws_size,
                              hipStream_t stream) {
    const float* pred   = (const float*)d_in[0];
    const float* target = (const float*)d_in[1];
    float* out = (float*)d_out;
    hipMemsetAsync(d_out, 0, sizeof(float) * (out_size > 0 ? out_size : 1), stream);
    const int nblocks = 32 * 64;   // 32 images x (4x16) tiles
    skel_conn_loss<<<nblocks, NT, 0, stream>>>(pred, target, out);
}

// Round 11
// 183.836 us; speedup vs baseline: 1.2206x; 1.0226x over previous
//
#include <hip/hip_runtime.h>

// ConnectivityLoss R11: fused single-sweep iteration (separable pooling).
// Per iteration: ONE barrier, ONE exchange phase (2 A-halo rows per wave
// boundary), rolling 3-row w-window instead of persistent Bv[5].
//   v[k] = vmin3(A[k-1..k+1]); w[k] = hpool_min(v[k])   (== minpool row k)
//   p[k] = vmax3(w[k-1..k+1]); mx[k] = hpool_max(p[k])  (== maxpool(minpool))
//   A[k] = max(A[k] - (mx[k] - w[k]), 0)
// EMPIRICAL RULES (R5/R7/R8/R9): launch_bounds stays (256,3); no big
// temporaries in divergent paths; one atomic per block; WRITE_SIZE ~64 KB
// is the no-spill tripwire.

#define IMG 512
#define TW  32            // output tile width  (16 x-tiles)
#define TH  128           // output tile height (4 y-tiles)
#define SKW 34            // skeleton stash cols [11,44]
#define SKH 130           // skeleton stash rows [11,140]
#define XR   68           // exchange row stride (floats, swizzle-friendly)
#define XSLOT (4*XR)      // 4 rows per wave: {A0,A1,A3,A4}
#define XHALF (4*XSLOT)   // 4 waves
#define NT  256

struct alignas(16) R8 { float v[8]; };

__device__ __forceinline__ float f3min(float a, float b, float c) {
    return fminf(fminf(a, b), c);
}
__device__ __forceinline__ float f3max(float a, float b, float c) {
    return fmaxf(fmaxf(a, b), c);
}
__device__ __forceinline__ float dpp_up1(float x) {   // lane i <- i-1
    int r = __builtin_amdgcn_update_dpp(
        0, __builtin_bit_cast(int, x), 0x111, 0xF, 0xF, true); // row_shr:1
    return __builtin_bit_cast(float, r);
}
__device__ __forceinline__ float dpp_dn1(float x) {   // lane i <- i+1
    int r = __builtin_amdgcn_update_dpp(
        0, __builtin_bit_cast(int, x), 0x101, 0xF, 0xF, true); // row_shl:1
    return __builtin_bit_cast(float, r);
}
__device__ __forceinline__ float bpermf(int addr, float x) {
    return __builtin_bit_cast(float,
        __builtin_amdgcn_ds_bpermute(addr, __builtin_bit_cast(int, x)));
}

// horizontal 3-tap on a (vertically pooled) row; le/ri from strip s-1/s+1
// (lane -8/+8). fixL/fixR: clamped-window at image cols 0/511.
template<bool MN>
__device__ __forceinline__ void hpool(const R8& r, R8& h, bool fixL, bool fixR,
                                      int aL, int aR) {
    float le = bpermf(aL, r.v[7]);
    float ri = bpermf(aR, r.v[0]);
    if (MN) {
        h.v[0] = f3min(le,     r.v[0], r.v[1]);
        h.v[1] = f3min(r.v[0], r.v[1], r.v[2]);
        h.v[2] = f3min(r.v[1], r.v[2], r.v[3]);
        h.v[3] = f3min(r.v[2], r.v[3], r.v[4]);
        h.v[4] = f3min(r.v[3], r.v[4], r.v[5]);
        h.v[5] = f3min(r.v[4], r.v[5], r.v[6]);
        h.v[6] = f3min(r.v[5], r.v[6], r.v[7]);
        h.v[7] = f3min(r.v[6], r.v[7], ri);
        if (fixL) h.v[4] = fminf(r.v[4], r.v[5]);   // gx==0: drop left tap
        if (fixR) h.v[3] = fminf(r.v[2], r.v[3]);   // gx==511: drop right tap
    } else {
        h.v[0] = f3max(le,     r.v[0], r.v[1]);
        h.v[1] = f3max(r.v[0], r.v[1], r.v[2]);
        h.v[2] = f3max(r.v[1], r.v[2], r.v[3]);
        h.v[3] = f3max(r.v[2], r.v[3], r.v[4]);
        h.v[4] = f3max(r.v[3], r.v[4], r.v[5]);
        h.v[5] = f3max(r.v[4], r.v[5], r.v[6]);
        h.v[6] = f3max(r.v[5], r.v[6], r.v[7]);
        h.v[7] = f3max(r.v[6], r.v[7], ri);
        if (fixL) h.v[4] = fmaxf(r.v[4], r.v[5]);
        if (fixR) h.v[3] = fmaxf(r.v[2], r.v[3]);
    }
}

__global__ __launch_bounds__(NT, 3)
void skel_conn_loss(const float* __restrict__ pred,
                    const float* __restrict__ target,
                    float* __restrict__ out)
{
    __shared__ float X[2*XHALF];         // A-halo exchange dbuf (8.7 KB)
    __shared__ float SKP[SKH*SKW];       // pred skeleton
    __shared__ float SKT[SKH*SKW];       // target skeleton
    __shared__ float red[4];

    const int tid  = threadIdx.x;
    const int wv   = tid >> 6;           // wave 0..3 owns rows 40w..40w+39
    const int lane = tid & 63;
    const int s    = lane >> 3;          // 8-col strip
    const int gq   = lane & 7;           // row group (5 rows); +-1 == lane+-1
    const int img  = blockIdx.x >> 6;
    const int rem  = blockIdx.x & 63;
    const int ty0  = (rem >> 4) * TH;
    const int tx0  = (rem & 15) * TW;

    const int c0  = 8*s;
    const int r0  = 40*wv + 5*gq;
    const int gx0 = tx0 - 12 + c0;
    const bool xin = (tx0 > 0) && (tx0 + TW < IMG);

    const bool lB = (tx0 == 0), rB = (tx0 + TW == IMG);
    const bool tB = (ty0 == 0), bB = (ty0 + TH == IMG);
    const bool fixL = lB && (s == 1);                // col 12 == gx 0
    const bool fixR = rB && (s == 5);                // col 43 == gx 511
    const bool vfT  = tB && (wv == 0) && (gq == 2);  // pr 12 == gy 0 (k==2)
    const bool vfB  = bB && (wv == 3) && (gq == 3);  // pr 139 == gy 511 (k==4)
    const int  sw   = 8*s + 4*(s >> 2);              // bank-swizzled exch col
    const int  aL   = ((lane - 8) & 63) * 4;         // bpermute addrs
    const int  aR   = ((lane + 8) & 63) * 4;

    R8 A[5];
    int xb = 0;

    #pragma unroll 1
    for (int t = 0; t < 2; ++t) {
        const float* __restrict__ src =
            (t ? target : pred) + (size_t)img * (IMG * IMG);

        // ---- load strip (addresses clamped; OOB values never consumed) ----
        #pragma unroll
        for (int i = 0; i < 5; ++i) {
            int gy = min(max(ty0 - 12 + r0 + i, 0), IMG - 1);
            const float* rp = src + gy * IMG;
            if (xin) {
                *(float4*)&A[i].v[0] = *(const float4*)(rp + gx0);
                *(float4*)&A[i].v[4] = *(const float4*)(rp + gx0 + 4);
            } else {
                #pragma unroll
                for (int j = 0; j < 8; ++j)
                    A[i].v[j] = rp[min(max(gx0 + j, 0), IMG - 1)];
            }
        }

        #pragma unroll 1
        for (int it = 0; it < 5; ++it) {
            float* Xb = X + xb * XHALF;
            // ---- post boundary A-rows (old values) for vertical halo ----
            if (gq == 0) {
                float* p = Xb + wv * XSLOT + sw;          // rows 0,1
                *(float4*)p            = *(const float4*)&A[0].v[0];
                *(float4*)(p + 4)      = *(const float4*)&A[0].v[4];
                *(float4*)(p + XR)     = *(const float4*)&A[1].v[0];
                *(float4*)(p + XR + 4) = *(const float4*)&A[1].v[4];
            }
            if (gq == 7) {
                float* p = Xb + wv * XSLOT + 2*XR + sw;   // rows 2,3
                *(float4*)p            = *(const float4*)&A[3].v[0];
                *(float4*)(p + 4)      = *(const float4*)&A[3].v[4];
                *(float4*)(p + XR)     = *(const float4*)&A[4].v[0];
                *(float4*)(p + XR + 4) = *(const float4*)&A[4].v[4];
            }
            __syncthreads();

            // ---- vertical halo: A[-2],A[-1],A[5],A[6] ----
            R8 am2, am1, ap5, ap6;
            #pragma unroll
            for (int j = 0; j < 8; ++j) {
                am2.v[j] = dpp_up1(A[3].v[j]);   // gq-1's A[3] = my pr-2
                am1.v[j] = dpp_up1(A[4].v[j]);   // gq-1's A[4] = my pr-1
                ap5.v[j] = dpp_dn1(A[0].v[j]);   // gq+1's A[0] = my pr+5
                ap6.v[j] = dpp_dn1(A[1].v[j]);   // gq+1's A[1] = my pr+6
            }
            if (gq == 0) {
                if (wv) {
                    const float* p = Xb + (wv - 1) * XSLOT + 2*XR + sw;
                    *(float4*)&am2.v[0] = *(const float4*)p;
                    *(float4*)&am2.v[4] = *(const float4*)(p + 4);
                    *(float4*)&am1.v[0] = *(const float4*)(p + XR);
                    *(float4*)&am1.v[4] = *(const float4*)(p + XR + 4);
                } else { am2 = A[0]; am1 = A[0]; }  // tile-edge garbage margin
            }
            if (gq == 7) {
                if (wv < 3) {
                    const float* p = Xb + (wv + 1) * XSLOT + sw;
                    *(float4*)&ap5.v[0] = *(const float4*)p;
                    *(float4*)&ap5.v[4] = *(const float4*)(p + 4);
                    *(float4*)&ap6.v[0] = *(const float4*)(p + XR);
                    *(float4*)&ap6.v[4] = *(const float4*)(p + XR + 4);
                } else { ap5 = A[4]; ap6 = A[4]; }
            }

            // ---- fused sweep: rolling w-window (wA,wB,wC), update A[k] ----
            R8 vt, wA, wB, wC, pp, mx;
            #define VMIN3(d, x, y, z)                                          \
                _Pragma("unroll")                                              \
                for (int j = 0; j < 8; ++j) d.v[j] = f3min((x).v[j], (y).v[j], (z).v[j]);
            #define UPD(i, CEN)                                                \
                _Pragma("unroll")                                              \
                for (int j = 0; j < 8; ++j) {                                  \
                    float ct = mx.v[j] - (CEN).v[j];                           \
                    A[i].v[j] = fmaxf(A[i].v[j] - ct, 0.0f);                   \
                }
            VMIN3(vt, am2, am1, A[0])                     // v[-1]
            hpool<true>(vt, wA, fixL, fixR, aL, aR);      // w[-1]
            VMIN3(vt, am1, A[0], A[1])                    // v[0]
            hpool<true>(vt, wB, fixL, fixR, aL, aR);      // w[0]
            VMIN3(vt, A[0], A[1], A[2])                   // v[1]
            hpool<true>(vt, wC, fixL, fixR, aL, aR);      // w[1]
            // k=0: window (w[-1],w[0],w[1]) = (wA,wB,wC), center wB
            #pragma unroll
            for (int j = 0; j < 8; ++j) pp.v[j] = f3max(wA.v[j], wB.v[j], wC.v[j]);
            hpool<false>(pp, mx, fixL, fixR, aL, aR);
            UPD(0, wB)
            // v[2] -> wA (vfT: pr 12 drops pr 11 tap = A[1])
            #pragma unroll
            for (int j = 0; j < 8; ++j)
                vt.v[j] = vfT ? fminf(A[2].v[j], A[3].v[j])
                              : f3min(A[1].v[j], A[2].v[j], A[3].v[j]);
            hpool<true>(vt, wA, fixL, fixR, aL, aR);      // w[2]
            // k=1: window (wB,wC,wA), center wC
            #pragma unroll
            for (int j = 0; j < 8; ++j) pp.v[j] = f3max(wB.v[j], wC.v[j], wA.v[j]);
            hpool<false>(pp, mx, fixL, fixR, aL, aR);
            UPD(1, wC)
            VMIN3(vt, A[2], A[3], A[4])                   // v[3]
            hpool<true>(vt, wB, fixL, fixR, aL, aR);      // w[3]
            // k=2: window (wC,wA,wB), center wA; vfT drops w[1]=wC
            #pragma unroll
            for (int j = 0; j < 8; ++j)
                pp.v[j] = vfT ? fmaxf(wA.v[j], wB.v[j])
                              : f3max(wC.v[j], wA.v[j], wB.v[j]);
            hpool<false>(pp, mx, fixL, fixR, aL, aR);
            UPD(2, wA)
            // v[4] -> wC (vfB: pr 139 drops pr 140 tap = ap5)
            #pragma unroll
            for (int j = 0; j < 8; ++j)
                vt.v[j] = vfB ? fminf(A[3].v[j], A[4].v[j])
                              : f3min(A[3].v[j], A[4].v[j], ap5.v[j]);
            hpool<true>(vt, wC, fixL, fixR, aL, aR);      // w[4]
            // k=3: window (wA,wB,wC), center wB
            #pragma unroll
            for (int j = 0; j < 8; ++j) pp.v[j] = f3max(wA.v[j], wB.v[j], wC.v[j]);
            hpool<false>(pp, mx, fixL, fixR, aL, aR);
            UPD(3, wB)
            VMIN3(vt, A[4], ap5, ap6)                     // v[5]
            hpool<true>(vt, wA, fixL, fixR, aL, aR);      // w[5]
            // k=4: window (wB,wC,wA), center wC; vfB drops w[5]=wA
            #pragma unroll
            for (int j = 0; j < 8; ++j)
                pp.v[j] = vfB ? fmaxf(wB.v[j], wC.v[j])
                              : f3max(wB.v[j], wC.v[j], wA.v[j]);
            hpool<false>(pp, mx, fixL, fixR, aL, aR);
            UPD(4, wC)
            #undef VMIN3
            #undef UPD
            xb ^= 1;
        }

        // ---- stash skeleton region [11,140]x[11,44] to LDS ----
        {
            float* SK = t ? SKT : SKP;
            #pragma unroll
            for (int i = 0; i < 5; ++i) {
                int pr = r0 + i;
                if (pr >= 11 && pr <= 140) {
                    #pragma unroll
                    for (int j = 0; j < 8; ++j) {
                        int pc = c0 + j;
                        if (pc >= 11 && pc <= 44)
                            SK[(pr - 11) * SKW + (pc - 11)] = A[i].v[j];
                    }
                }
            }
        }
        __syncthreads();   // stash done; X safe to reuse next t
    }

    // ---- epilogue: rolling-column sumpool3 + indicators + loss ----
    const int cx  = tid & 31;
    const int ry0 = (tid >> 5) * 16;
    const int gx  = tx0 + cx;
    const float xl = (gx >= 1)      ? 1.0f : 0.0f;
    const float xr = (gx + 1 < IMG) ? 1.0f : 0.0f;

    auto hs = [&](const float* __restrict__ SK, int k) -> float {
        const float* p = SK + k * SKW + cx;
        return p[1] + xl * p[0] + xr * p[2];
    };

    float acc = 0.0f;
    float hp0, hp1, ht0, ht1;
    {
        float vT = ((unsigned)(ty0 + ry0 - 1) < IMG) ? 1.0f : 0.0f;
        hp0 = vT * hs(SKP, ry0);
        ht0 = vT * hs(SKT, ry0);
        hp1 = hs(SKP, ry0 + 1);
        ht1 = hs(SKT, ry0 + 1);
    }
    #pragma unroll
    for (int r = 0; r < 16; ++r) {
        int k2 = ry0 + r + 2;
        float vB = ((unsigned)(ty0 + k2 - 1) < IMG) ? 1.0f : 0.0f;
        float hp2 = vB * hs(SKP, k2);
        float ht2 = vB * hs(SKT, k2);
        float pn = hp0 + hp1 + hp2;
        float tn = ht0 + ht1 + ht2;
        float ps = SKP[(ry0 + r + 1) * SKW + cx + 1];
        float ts = SKT[(ry0 + r + 1) * SKW + cx + 1];
        float pon = (ps > 0.5f) ? 1.0f : 0.0f;
        float ton = (ts > 0.5f) ? 1.0f : 0.0f;
        float pe = (pn == 2.0f) ? pon : 0.0f;
        float te = (tn == 2.0f) ? ton : 0.0f;
        float pc = (pn >= 4.0f) ? pon : 0.0f;
        float tc = (tn >= 4.0f) ? ton : 0.0f;
        float ds = ps - ts, de = pe - te, dc = pc - tc;
        acc += 0.6f * ds * ds + 0.2f * (de * de + dc * dc);
        hp0 = hp1; hp1 = hp2;
        ht0 = ht1; ht1 = ht2;
    }

    // ---- block reduction -> ONE atomic per block ----
    #pragma unroll
    for (int off = 32; off >= 1; off >>= 1)
        acc += __shfl_down(acc, off, 64);
    if (lane == 0) red[wv] = acc;
    __syncthreads();
    if (tid == 0) {
        float sum = red[0] + red[1] + red[2] + red[3];
        atomicAdd(out, sum * (1.0f / 8388608.0f));  // N = 32*512*512 = 2^23
    }
}

extern "C" void kernel_launch(void* const* d_in, const int* in_sizes, int n_in,
                              void* d_out, int out_size, void* d_ws, size_t ws_size,
                              hipStream_t stream) {
    const float* pred   = (const float*)d_in[0];
    const float* target = (const float*)d_in[1];
    float* out = (float*)d_out;
    hipMemsetAsync(d_out, 0, sizeof(float) * (out_size > 0 ? out_size : 1), stream);
    const int nblocks = 32 * 64;   // 32 images x (4x16) tiles
    skel_conn_loss<<<nblocks, NT, 0, stream>>>(pred, target, out);
}

// Round 12
// 174.383 us; speedup vs baseline: 1.2868x; 1.0542x over previous
//
#include <hip/hip_runtime.h>

// ConnectivityLoss R12: R11 fused sweep, widened output tile (work-ratio cut).
// The 64-col strip region = 12 halo + 40 OUTPUT + 12 halo (was 32 output):
// same per-block work, 13 x-tiles instead of 16 -> 1664 blocks (0.8125x).
// Tile 12 is partial (cols 480..511 valid) -> epilogue masks gx>=512.
// EMPIRICAL RULES (R5/R7/R8/R9): launch_bounds stays (256,3); no big
// temporaries in divergent paths; one atomic per block; WRITE_SIZE ~64 KB
// is the no-spill tripwire.

#define IMG 512
#define OC  40            // output cols per tile (13 x-tiles; last partial)
#define TH  128           // output rows per tile (4 y-tiles)
#define TPI 52            // tiles per image = 13 * 4
#define SKW 42            // skeleton stash cols [11,52]
#define SKH 130           // skeleton stash rows [11,140]
#define XR   68           // exchange row stride (floats)
#define XSLOT (4*XR)      // 4 rows per wave: {A0,A1,A3,A4}
#define XHALF (4*XSLOT)   // 4 waves
#define NT  256

struct alignas(16) R8 { float v[8]; };

__device__ __forceinline__ float f3min(float a, float b, float c) {
    return fminf(fminf(a, b), c);
}
__device__ __forceinline__ float f3max(float a, float b, float c) {
    return fmaxf(fmaxf(a, b), c);
}
__device__ __forceinline__ float dpp_up1(float x) {   // lane i <- i-1
    int r = __builtin_amdgcn_update_dpp(
        0, __builtin_bit_cast(int, x), 0x111, 0xF, 0xF, true); // row_shr:1
    return __builtin_bit_cast(float, r);
}
__device__ __forceinline__ float dpp_dn1(float x) {   // lane i <- i+1
    int r = __builtin_amdgcn_update_dpp(
        0, __builtin_bit_cast(int, x), 0x101, 0xF, 0xF, true); // row_shl:1
    return __builtin_bit_cast(float, r);
}
__device__ __forceinline__ float bpermf(int addr, float x) {
    return __builtin_bit_cast(float,
        __builtin_amdgcn_ds_bpermute(addr, __builtin_bit_cast(int, x)));
}

// horizontal 3-tap on a (vertically pooled) row; le/ri from strip s-1/s+1
// (lane -8/+8). fixL/fixR: clamped-window at image cols 0/511.
template<bool MN>
__device__ __forceinline__ void hpool(const R8& r, R8& h, bool fixL, bool fixR,
                                      int aL, int aR) {
    float le = bpermf(aL, r.v[7]);
    float ri = bpermf(aR, r.v[0]);
    if (MN) {
        h.v[0] = f3min(le,     r.v[0], r.v[1]);
        h.v[1] = f3min(r.v[0], r.v[1], r.v[2]);
        h.v[2] = f3min(r.v[1], r.v[2], r.v[3]);
        h.v[3] = f3min(r.v[2], r.v[3], r.v[4]);
        h.v[4] = f3min(r.v[3], r.v[4], r.v[5]);
        h.v[5] = f3min(r.v[4], r.v[5], r.v[6]);
        h.v[6] = f3min(r.v[5], r.v[6], r.v[7]);
        h.v[7] = f3min(r.v[6], r.v[7], ri);
        if (fixL) h.v[4] = fminf(r.v[4], r.v[5]);   // gx==0: drop left tap
        if (fixR) h.v[3] = fminf(r.v[2], r.v[3]);   // gx==511: drop right tap
    } else {
        h.v[0] = f3max(le,     r.v[0], r.v[1]);
        h.v[1] = f3max(r.v[0], r.v[1], r.v[2]);
        h.v[2] = f3max(r.v[1], r.v[2], r.v[3]);
        h.v[3] = f3max(r.v[2], r.v[3], r.v[4]);
        h.v[4] = f3max(r.v[3], r.v[4], r.v[5]);
        h.v[5] = f3max(r.v[4], r.v[5], r.v[6]);
        h.v[6] = f3max(r.v[5], r.v[6], r.v[7]);
        h.v[7] = f3max(r.v[6], r.v[7], ri);
        if (fixL) h.v[4] = fmaxf(r.v[4], r.v[5]);
        if (fixR) h.v[3] = fmaxf(r.v[2], r.v[3]);
    }
}

__global__ __launch_bounds__(NT, 3)
void skel_conn_loss(const float* __restrict__ pred,
                    const float* __restrict__ target,
                    float* __restrict__ out)
{
    __shared__ float X[2*XHALF];         // A-halo exchange dbuf (8.7 KB)
    __shared__ float SKP[SKH*SKW];       // pred skeleton (21.8 KB)
    __shared__ float SKT[SKH*SKW];       // target skeleton
    __shared__ float red[4];

    const int tid  = threadIdx.x;
    const int wv   = tid >> 6;           // wave 0..3 owns rows 40w..40w+39
    const int lane = tid & 63;
    const int s    = lane >> 3;          // 8-col strip
    const int gq   = lane & 7;           // row group (5 rows); +-1 == lane+-1
    const int img  = blockIdx.x / TPI;
    const int rem  = blockIdx.x % TPI;
    const int ty0  = (rem / 13) * TH;
    const int tx0  = (rem % 13) * OC;

    const int c0  = 8*s;
    const int r0  = 40*wv + 5*gq;
    const int gx0 = tx0 - 12 + c0;
    const bool xin = (tx0 > 0) && (tx0 + 52 <= IMG);   // strip fully in-image

    const bool lB = (tx0 == 0), rB = (tx0 + OC >= IMG);
    const bool tB = (ty0 == 0), bB = (ty0 + TH == IMG);
    const bool fixL = lB && (s == 1);                // c 12 == gx 0
    const bool fixR = rB && (s == 5);                // c 43 == gx 511
    const bool vfT  = tB && (wv == 0) && (gq == 2);  // pr 12 == gy 0 (k==2)
    const bool vfB  = bB && (wv == 3) && (gq == 3);  // pr 139 == gy 511 (k==4)
    const int  sw   = 8*s + 4*(s >> 2);              // bank-swizzled exch col
    const int  aL   = ((lane - 8) & 63) * 4;         // bpermute addrs
    const int  aR   = ((lane + 8) & 63) * 4;

    R8 A[5];
    int xb = 0;

    #pragma unroll 1
    for (int t = 0; t < 2; ++t) {
        const float* __restrict__ src =
            (t ? target : pred) + (size_t)img * (IMG * IMG);

        // ---- load strip (addresses clamped; OOB values never consumed) ----
        #pragma unroll
        for (int i = 0; i < 5; ++i) {
            int gy = min(max(ty0 - 12 + r0 + i, 0), IMG - 1);
            const float* rp = src + gy * IMG;
            if (xin) {
                *(float4*)&A[i].v[0] = *(const float4*)(rp + gx0);
                *(float4*)&A[i].v[4] = *(const float4*)(rp + gx0 + 4);
            } else {
                #pragma unroll
                for (int j = 0; j < 8; ++j)
                    A[i].v[j] = rp[min(max(gx0 + j, 0), IMG - 1)];
            }
        }

        #pragma unroll 1
        for (int it = 0; it < 5; ++it) {
            float* Xb = X + xb * XHALF;
            // ---- post boundary A-rows (old values) for vertical halo ----
            if (gq == 0) {
                float* p = Xb + wv * XSLOT + sw;          // rows 0,1
                *(float4*)p            = *(const float4*)&A[0].v[0];
                *(float4*)(p + 4)      = *(const float4*)&A[0].v[4];
                *(float4*)(p + XR)     = *(const float4*)&A[1].v[0];
                *(float4*)(p + XR + 4) = *(const float4*)&A[1].v[4];
            }
            if (gq == 7) {
                float* p = Xb + wv * XSLOT + 2*XR + sw;   // rows 2,3
                *(float4*)p            = *(const float4*)&A[3].v[0];
                *(float4*)(p + 4)      = *(const float4*)&A[3].v[4];
                *(float4*)(p + XR)     = *(const float4*)&A[4].v[0];
                *(float4*)(p + XR + 4) = *(const float4*)&A[4].v[4];
            }
            __syncthreads();

            // ---- vertical halo: A[-2],A[-1],A[5],A[6] ----
            R8 am2, am1, ap5, ap6;
            #pragma unroll
            for (int j = 0; j < 8; ++j) {
                am2.v[j] = dpp_up1(A[3].v[j]);   // gq-1's A[3] = my pr-2
                am1.v[j] = dpp_up1(A[4].v[j]);   // gq-1's A[4] = my pr-1
                ap5.v[j] = dpp_dn1(A[0].v[j]);   // gq+1's A[0] = my pr+5
                ap6.v[j] = dpp_dn1(A[1].v[j]);   // gq+1's A[1] = my pr+6
            }
            if (gq == 0) {
                if (wv) {
                    const float* p = Xb + (wv - 1) * XSLOT + 2*XR + sw;
                    *(float4*)&am2.v[0] = *(const float4*)p;
                    *(float4*)&am2.v[4] = *(const float4*)(p + 4);
                    *(float4*)&am1.v[0] = *(const float4*)(p + XR);
                    *(float4*)&am1.v[4] = *(const float4*)(p + XR + 4);
                } else { am2 = A[0]; am1 = A[0]; }  // tile-edge garbage margin
            }
            if (gq == 7) {
                if (wv < 3) {
                    const float* p = Xb + (wv + 1) * XSLOT + sw;
                    *(float4*)&ap5.v[0] = *(const float4*)p;
                    *(float4*)&ap5.v[4] = *(const float4*)(p + 4);
                    *(float4*)&ap6.v[0] = *(const float4*)(p + XR);
                    *(float4*)&ap6.v[4] = *(const float4*)(p + XR + 4);
                } else { ap5 = A[4]; ap6 = A[4]; }
            }

            // ---- fused sweep: rolling w-window (wA,wB,wC), update A[k] ----
            R8 vt, wA, wB, wC, pp, mx;
            #define VMIN3(d, x, y, z)                                          \
                _Pragma("unroll")                                              \
                for (int j = 0; j < 8; ++j) d.v[j] = f3min((x).v[j], (y).v[j], (z).v[j]);
            #define UPD(i, CEN)                                                \
                _Pragma("unroll")                                              \
                for (int j = 0; j < 8; ++j) {                                  \
                    float ct = mx.v[j] - (CEN).v[j];                           \
                    A[i].v[j] = fmaxf(A[i].v[j] - ct, 0.0f);                   \
                }
            VMIN3(vt, am2, am1, A[0])                     // v[-1]
            hpool<true>(vt, wA, fixL, fixR, aL, aR);      // w[-1]
            VMIN3(vt, am1, A[0], A[1])                    // v[0]
            hpool<true>(vt, wB, fixL, fixR, aL, aR);      // w[0]
            VMIN3(vt, A[0], A[1], A[2])                   // v[1]
            hpool<true>(vt, wC, fixL, fixR, aL, aR);      // w[1]
            // k=0: window (wA,wB,wC), center wB
            #pragma unroll
            for (int j = 0; j < 8; ++j) pp.v[j] = f3max(wA.v[j], wB.v[j], wC.v[j]);
            hpool<false>(pp, mx, fixL, fixR, aL, aR);
            UPD(0, wB)
            // v[2] -> wA (vfT: pr 12 drops pr 11 tap = A[1])
            #pragma unroll
            for (int j = 0; j < 8; ++j)
                vt.v[j] = vfT ? fminf(A[2].v[j], A[3].v[j])
                              : f3min(A[1].v[j], A[2].v[j], A[3].v[j]);
            hpool<true>(vt, wA, fixL, fixR, aL, aR);      // w[2]
            // k=1: window (wB,wC,wA), center wC
            #pragma unroll
            for (int j = 0; j < 8; ++j) pp.v[j] = f3max(wB.v[j], wC.v[j], wA.v[j]);
            hpool<false>(pp, mx, fixL, fixR, aL, aR);
            UPD(1, wC)
            VMIN3(vt, A[2], A[3], A[4])                   // v[3]
            hpool<true>(vt, wB, fixL, fixR, aL, aR);      // w[3]
            // k=2: window (wC,wA,wB), center wA; vfT drops w[1]=wC
            #pragma unroll
            for (int j = 0; j < 8; ++j)
                pp.v[j] = vfT ? fmaxf(wA.v[j], wB.v[j])
                              : f3max(wC.v[j], wA.v[j], wB.v[j]);
            hpool<false>(pp, mx, fixL, fixR, aL, aR);
            UPD(2, wA)
            // v[4] -> wC (vfB: pr 139 drops pr 140 tap = ap5)
            #pragma unroll
            for (int j = 0; j < 8; ++j)
                vt.v[j] = vfB ? fminf(A[3].v[j], A[4].v[j])
                              : f3min(A[3].v[j], A[4].v[j], ap5.v[j]);
            hpool<true>(vt, wC, fixL, fixR, aL, aR);      // w[4]
            // k=3: window (wA,wB,wC), center wB
            #pragma unroll
            for (int j = 0; j < 8; ++j) pp.v[j] = f3max(wA.v[j], wB.v[j], wC.v[j]);
            hpool<false>(pp, mx, fixL, fixR, aL, aR);
            UPD(3, wB)
            VMIN3(vt, A[4], ap5, ap6)                     // v[5]
            hpool<true>(vt, wA, fixL, fixR, aL, aR);      // w[5]
            // k=4: window (wB,wC,wA), center wC; vfB drops w[5]=wA
            #pragma unroll
            for (int j = 0; j < 8; ++j)
                pp.v[j] = vfB ? fmaxf(wB.v[j], wC.v[j])
                              : f3max(wB.v[j], wC.v[j], wA.v[j]);
            hpool<false>(pp, mx, fixL, fixR, aL, aR);
            UPD(4, wC)
            #undef VMIN3
            #undef UPD
            xb ^= 1;
        }

        // ---- stash skeleton region [11,140]x[11,52] to LDS ----
        {
            float* SK = t ? SKT : SKP;
            #pragma unroll
            for (int i = 0; i < 5; ++i) {
                int pr = r0 + i;
                if (pr >= 11 && pr <= 140) {
                    #pragma unroll
                    for (int j = 0; j < 8; ++j) {
                        int pc = c0 + j;
                        if (pc >= 11 && pc <= 52)
                            SK[(pr - 11) * SKW + (pc - 11)] = A[i].v[j];
                    }
                }
            }
        }
        __syncthreads();   // stash done; X safe to reuse next t
    }

    // ---- epilogue: rolling-column sumpool3 + indicators + loss ----
    // thread = column cx (0..39), 6 row-groups of <=22. SK row k holds
    // global row ty0 + k - 1. Tile-12 cols gx>=512 masked by xv.
    const int cx  = tid % OC;
    const int rg  = tid / OC;            // 0..6 (rg==6 idle)
    float acc = 0.0f;
    if (rg < 6) {
        const int ry0 = rg * 22;
        const int cnt = min(22, TH - ry0);   // 22,22,22,22,22,18
        const int gx  = tx0 + cx;
        const float xv = (gx < IMG)     ? 1.0f : 0.0f;
        const float xl = (gx >= 1)      ? 1.0f : 0.0f;
        const float xr = (gx + 1 < IMG) ? 1.0f : 0.0f;

        auto hs = [&](const float* __restrict__ SK, int k) -> float {
            const float* p = SK + k * SKW + cx;
            return p[1] + xl * p[0] + xr * p[2];
        };

        float hp0, hp1, ht0, ht1;
        {
            float vT = ((unsigned)(ty0 + ry0 - 1) < IMG) ? 1.0f : 0.0f;
            hp0 = vT * hs(SKP, ry0);
            ht0 = vT * hs(SKT, ry0);
            hp1 = hs(SKP, ry0 + 1);
            ht1 = hs(SKT, ry0 + 1);
        }
        #pragma unroll 1
        for (int r = 0; r < cnt; ++r) {
            int k2 = ry0 + r + 2;
            float vB = ((unsigned)(ty0 + k2 - 1) < IMG) ? 1.0f : 0.0f;
            float hp2 = vB * hs(SKP, k2);
            float ht2 = vB * hs(SKT, k2);
            float pn = hp0 + hp1 + hp2;
            float tn = ht0 + ht1 + ht2;
            float ps = SKP[(ry0 + r + 1) * SKW + cx + 1];
            float ts = SKT[(ry0 + r + 1) * SKW + cx + 1];
            float pon = (ps > 0.5f) ? 1.0f : 0.0f;
            float ton = (ts > 0.5f) ? 1.0f : 0.0f;
            float pe = (pn == 2.0f) ? pon : 0.0f;
            float te = (tn == 2.0f) ? ton : 0.0f;
            float pc = (pn >= 4.0f) ? pon : 0.0f;
            float tc = (tn >= 4.0f) ? ton : 0.0f;
            float ds = ps - ts, de = pe - te, dc = pc - tc;
            acc += xv * (0.6f * ds * ds + 0.2f * (de * de + dc * dc));
            hp0 = hp1; hp1 = hp2;
            ht0 = ht1; ht1 = ht2;
        }
    }

    // ---- block reduction -> ONE atomic per block (R9: per-wave atomics
    // serialize cross-XCD, +100us) ----
    #pragma unroll
    for (int off = 32; off >= 1; off >>= 1)
        acc += __shfl_down(acc, off, 64);
    if (lane == 0) red[wv] = acc;
    __syncthreads();
    if (tid == 0) {
        float sum = red[0] + red[1] + red[2] + red[3];
        atomicAdd(out, sum * (1.0f / 8388608.0f));  // N = 32*512*512 = 2^23
    }
}

extern "C" void kernel_launch(void* const* d_in, const int* in_sizes, int n_in,
                              void* d_out, int out_size, void* d_ws, size_t ws_size,
                              hipStream_t stream) {
    const float* pred   = (const float*)d_in[0];
    const float* target = (const float*)d_in[1];
    float* out = (float*)d_out;
    hipMemsetAsync(d_out, 0, sizeof(float) * (out_size > 0 ? out_size : 1), stream);
    const int nblocks = 32 * TPI;   // 32 images x (4x13) tiles = 1664
    skel_conn_loss<<<nblocks, NT, 0, stream>>>(pred, target, out);
}